// Round 1
// baseline (220.984 us; speedup 1.0000x reference)
//
#include <hip/hip_runtime.h>
#include <hip/hip_bf16.h>
#include <math.h>

// Problem constants (fixed by setup_inputs): B=2, Cin=Cout=64, H=W=128
#define HWSZ 16384   // H*W
#define NPIX 32768   // B*H*W

// ---------------- Kernel 1: pooled mean over H,W per (b,c) ----------------
__global__ __launch_bounds__(256) void k_pool(const float* __restrict__ inp,
                                              float* __restrict__ pooled) {
    int bc = blockIdx.x;                       // 0..127 = b*64+c
    const float* p = inp + (size_t)bc * HWSZ;
    float s = 0.f;
    for (int i = threadIdx.x; i < HWSZ; i += 256) s += p[i];
#pragma unroll
    for (int off = 32; off; off >>= 1) s += __shfl_down(s, off, 64);
    __shared__ float ls[4];
    if ((threadIdx.x & 63) == 0) ls[threadIdx.x >> 6] = s;
    __syncthreads();
    if (threadIdx.x == 0)
        pooled[bc] = (ls[0] + ls[1] + ls[2] + ls[3]) * (1.0f / 16384.0f);
}

// ---------------- Kernel 2: r = sigmoid(sum_b pooled @ fc_w^T + fc_b) -> alpha[8]
__global__ void k_r(const float* __restrict__ pooled,
                    const float* __restrict__ fc_w,
                    const float* __restrict__ fc_b,
                    float* __restrict__ alpha) {
    int c = threadIdx.x;                      // 64 threads = 1 wave
    float s = pooled[c] + pooled[64 + c];     // sum over batch of means
#pragma unroll
    for (int j = 0; j < 4; j++) {
        float v = s * fc_w[j * 64 + c];
#pragma unroll
        for (int off = 32; off; off >>= 1) v += __shfl_down(v, off, 64);
        if (c == 0) {
            float z = v + fc_b[j];
            float r = 1.0f / (1.0f + expf(-z));
            alpha[2 * j]     = r;     // q even: alpha = r_j
            alpha[2 * j + 1] = 1.0f;  // q odd:  alpha = 1
        }
    }
}

// ---------------- Kernel 3: transpose weight [o][k] -> [k][o] (k = c*9+j) ----
__global__ __launch_bounds__(256) void k_wt(const float* __restrict__ w,
                                            float* __restrict__ wT) {
    int i = blockIdx.x * 256 + threadIdx.x;   // 36864 = 576*64
    if (i < 36864) {
        int o = i & 63;
        int k = i >> 6;
        wT[i] = w[o * 576 + k];
    }
}

// ---------------- Kernel 4: deform-sample + circle8 blend -> E[c*9+j][pixel] (bf16)
__global__ __launch_bounds__(256) void k_sample(const float* __restrict__ inp,
                                                const float* __restrict__ off,
                                                const float* __restrict__ msk,
                                                const float* __restrict__ w8,
                                                const float* __restrict__ alpha,
                                                __hip_bfloat16* __restrict__ E) {
    const int tid = threadIdx.x;
    const int pl  = tid & 63;      // pixel lane (64 consecutive pixels per block)
    const int cg  = tid >> 6;      // channel group 0..3 (16 channels each)
    const int p   = blockIdx.x * 64 + pl;       // global pixel 0..32767
    const int b   = p >> 14;
    const int hw  = p & (HWSZ - 1);
    const int h   = hw >> 7;
    const int w   = hw & 127;
    const int sp  = h * 128 + w;

    // ---- per-pixel tap setup (recomputed by each of the 4 cg waves; cheap) ----
    float W00[9], W01[9], W10[9], W11[9];
    int   O00[9], O01[9], O10[9], O11[9];
    const float* offb = off + (size_t)b * 18 * HWSZ + sp;
    const float* mb   = msk + (size_t)b * 9 * HWSZ + sp;
#pragma unroll
    for (int k = 0; k < 9; k++) {
        float oy = offb[(2 * k) * HWSZ];
        float ox = offb[(2 * k + 1) * HWSZ];
        float m  = mb[k * HWSZ];
        float py = (float)(h + k / 3 - 1) + oy;
        float px = (float)(w + k % 3 - 1) + ox;
        float fy = floorf(py), fx = floorf(px);
        float ly = py - fy, lx = px - fx;
        int iy0 = (int)fy, ix0 = (int)fx;
        int iy1 = iy0 + 1, ix1 = ix0 + 1;
        bool vy0 = ((unsigned)iy0 < 128u), vy1 = ((unsigned)iy1 < 128u);
        bool vx0 = ((unsigned)ix0 < 128u), vx1 = ((unsigned)ix1 < 128u);
        float hy = 1.0f - ly, hx = 1.0f - lx;
        W00[k] = (vy0 && vx0) ? hy * hx * m : 0.0f;
        W01[k] = (vy0 && vx1) ? hy * lx * m : 0.0f;
        W10[k] = (vy1 && vx0) ? ly * hx * m : 0.0f;
        W11[k] = (vy1 && vx1) ? ly * lx * m : 0.0f;
        int cy0 = min(max(iy0, 0), 127), cy1 = min(max(iy1, 0), 127);
        int cx0 = min(max(ix0, 0), 127), cx1 = min(max(ix1, 0), 127);
        O00[k] = cy0 * 128 + cx0;  O01[k] = cy0 * 128 + cx1;
        O10[k] = cy1 * 128 + cx0;  O11[k] = cy1 * 128 + cx1;
    }

    // per-pixel blend coefficients
    float u[8], vv[4];
    const float* w8b = w8 + (size_t)b * 8 * HWSZ + sp;
#pragma unroll
    for (int q = 0; q < 8; q++) {
        float x = w8b[q * HWSZ];
        float a = alpha[q];                // wave-uniform scalar load
        u[q] = x * a;
        if ((q & 1) == 0) vv[q >> 1] = x * (1.0f - a);
    }

    // Pinv_q = P_{(8-q)%8} (verified by explicit inversion)
    constexpr int PINV[8][9] = {
        {0,1,2,3,4,5,6,7,8},
        {1,2,5,0,4,8,3,6,7},
        {2,5,8,1,4,7,0,3,6},
        {5,8,7,2,4,6,1,0,3},
        {8,7,6,5,4,3,2,1,0},
        {7,6,3,8,4,0,5,2,1},
        {6,3,0,7,4,1,8,5,2},
        {3,0,1,6,4,2,7,8,5}};
    const float SA = 0.5f;          // S^2
    const float SB = 0.20710678f;   // S*(1-S)
    const float SC = 0.08578644f;   // (1-S)^2

    const float* ipb = inp + (size_t)(b * 64 + cg * 16) * HWSZ;
    for (int cc = 0; cc < 16; cc++) {
        const float* ip = ipb + (size_t)cc * HWSZ;
        float sam[9];
#pragma unroll
        for (int k = 0; k < 9; k++)
            sam[k] = W00[k] * ip[O00[k]] + W01[k] * ip[O01[k]] +
                     W10[k] * ip[O10[k]] + W11[k] * ip[O11[k]];
        float A[9], Bv[9];
#pragma unroll
        for (int t = 0; t < 9; t++) {
            float a = 0.f, bb = 0.f;
#pragma unroll
            for (int q = 0; q < 8; q++) a += u[q] * sam[PINV[q][t]];
#pragma unroll
            for (int i = 0; i < 4; i++) bb += vv[i] * sam[PINV[2 * i][t]];
            A[t] = a; Bv[t] = bb;
        }
        float Ev[9];
        Ev[0] = SA * A[0] + Bv[0];
        Ev[1] = A[1] + SB * (A[0] + A[2]) + Bv[1];
        Ev[2] = SA * A[2] + Bv[2];
        Ev[3] = A[3] + SB * (A[0] + A[6]) + Bv[3];
        Ev[4] = A[4] + SC * (A[0] + A[2] + A[6] + A[8]) + Bv[4];
        Ev[5] = A[5] + SB * (A[2] + A[8]) + Bv[5];
        Ev[6] = SA * A[6] + Bv[6];
        Ev[7] = A[7] + SB * (A[6] + A[8]) + Bv[7];
        Ev[8] = SA * A[8] + Bv[8];
        int c = cg * 16 + cc;
#pragma unroll
        for (int j = 0; j < 9; j++)
            E[(size_t)(c * 9 + j) * NPIX + p] = __float2bfloat16(Ev[j]);
    }
}

// ---------------- Kernel 5: out[p][o] = sum_k wT[k][o] * E[k][p] + bias_eff ----
__global__ __launch_bounds__(256) void k_gemm(const __hip_bfloat16* __restrict__ E,
                                              const float* __restrict__ wT,
                                              const float* __restrict__ w8,
                                              const float* __restrict__ bias,
                                              float* __restrict__ out) {
    const int tid = threadIdx.x;
    const int pl  = tid & 63;
    const int og  = __builtin_amdgcn_readfirstlane(tid >> 6);  // force uniform -> s_loads
    const int p   = blockIdx.x * 64 + pl;

    float acc[16];
#pragma unroll
    for (int i = 0; i < 16; i++) acc[i] = 0.f;

#pragma unroll 4
    for (int k = 0; k < 576; k++) {
        float e = __bfloat162float(E[(size_t)k * NPIX + p]);
        const float* wrow = wT + k * 64 + og * 16;
#pragma unroll
        for (int i = 0; i < 16; i++) acc[i] += e * wrow[i];
    }

    const int b  = p >> 14;
    const int sp = p & (HWSZ - 1);
    const float* w8b = w8 + (size_t)b * 8 * HWSZ + sp;
    float w8v[8];
#pragma unroll
    for (int q = 0; q < 8; q++) w8v[q] = w8b[q * HWSZ];

#pragma unroll
    for (int i = 0; i < 16; i++) {
        int o = og * 16 + i;
        float bv = 0.f;
#pragma unroll
        for (int q = 0; q < 8; q++) bv += w8v[q] * bias[q * 64 + o];
        out[(size_t)(b * 64 + o) * HWSZ + sp] = acc[i] + bv;
    }
}

// ---------------- Launch ----------------
extern "C" void kernel_launch(void* const* d_in, const int* in_sizes, int n_in,
                              void* d_out, int out_size, void* d_ws, size_t ws_size,
                              hipStream_t stream) {
    const float* input  = (const float*)d_in[0];
    const float* offset = (const float*)d_in[1];
    const float* mask   = (const float*)d_in[2];
    const float* w_c8   = (const float*)d_in[3];
    const float* weight = (const float*)d_in[4];
    const float* bias   = (const float*)d_in[5];
    const float* fc_w   = (const float*)d_in[6];
    const float* fc_b   = (const float*)d_in[7];
    float* out = (float*)d_out;

    float* wsf    = (float*)d_ws;
    float* wT     = wsf;              // 36864 floats
    float* pooled = wsf + 36864;      // 128 floats
    float* alpha  = wsf + 36992;      // 8 floats
    __hip_bfloat16* E = (__hip_bfloat16*)(wsf + 37120);  // 576*32768 bf16 = 36 MiB

    k_pool<<<dim3(128), dim3(256), 0, stream>>>(input, pooled);
    k_r<<<dim3(1), dim3(64), 0, stream>>>(pooled, fc_w, fc_b, alpha);
    k_wt<<<dim3(144), dim3(256), 0, stream>>>(weight, wT);
    k_sample<<<dim3(512), dim3(256), 0, stream>>>(input, offset, mask, w_c8, alpha, E);
    k_gemm<<<dim3(512), dim3(256), 0, stream>>>(E, wT, w_c8, bias, out);
}